// Round 6
// baseline (484.947 us; speedup 1.0000x reference)
//
#include <hip/hip_runtime.h>
#include <stdint.h>

#define H_ 16
#define D_ 1024
#define SPLIT_ 4
#define DK_ 64
#define B_ 4
#define SEQ_ 4096
#define L_ 1024

// 0.125 * log2(e): folded into Wq/bq so attn softmax runs in exp2 domain.
#define QSC 0.18033688f

typedef unsigned short ushort_t;
typedef __attribute__((ext_vector_type(8))) short short8;
typedef __attribute__((ext_vector_type(4))) float floatx4;
typedef __attribute__((ext_vector_type(4))) unsigned short ushortx4;

__device__ __forceinline__ ushort_t f2bf(float f) {   // RNE
  union { float f; unsigned u; } cv; cv.f = f;
  unsigned u = cv.u;
  return (ushort_t)((u + 0x7fffu + ((u >> 16) & 1u)) >> 16);
}

// pack two floats -> bf16x2 (truncating) in one v_perm_b32
__device__ __forceinline__ uint32_t pack_bf_trunc(float x, float y) {
#if __has_builtin(__builtin_amdgcn_perm)
  return __builtin_amdgcn_perm(__float_as_uint(y), __float_as_uint(x), 0x07060302u);
#else
  return (__float_as_uint(y) & 0xffff0000u) | (__float_as_uint(x) >> 16);
#endif
}

__device__ __forceinline__ float exp2f_fast(float x) {
#if __has_builtin(__builtin_amdgcn_exp2f)
  return __builtin_amdgcn_exp2f(x);
#else
  return exp2f(x);
#endif
}

__device__ __forceinline__ float fmax3(float a, float b, float c) {
  return fmaxf(fmaxf(a, b), c);   // clang fuses to v_max3_f32
}

// async 16B global->LDS (dest must be wave-uniform base + lane*16)
__device__ __forceinline__ void gl2lds16(const ushort_t* g, ushort_t* l) {
  __builtin_amdgcn_global_load_lds(
      (const __attribute__((address_space(1))) uint32_t*)g,
      (__attribute__((address_space(3))) uint32_t*)l, 16, 0, 0);
}

// raw workgroup barrier WITHOUT the compiler's vmcnt(0) drain.
__device__ __forceinline__ void wave_barrier() {
  asm volatile("" ::: "memory");
  __builtin_amdgcn_s_barrier();
  asm volatile("" ::: "memory");
}

// ------------- x: fp32 -> bf16 (contiguous) ---------------------------------
__global__ __launch_bounds__(256) void convert_x(const float* __restrict__ X,
                                                 ushort_t* __restrict__ Y) {
  const int i = blockIdx.x * 256 + threadIdx.x;
  const float4 v = ((const float4*)X)[i];
  ushortx4 o;
  o[0] = f2bf(v.x); o[1] = f2bf(v.y); o[2] = f2bf(v.z); o[3] = f2bf(v.w);
  ((ushortx4*)Y)[i] = o;
}

// ------------- all 4 weights: W[s][d][e] fp32 -> Wt[mat][s][e][d] bf16 ------
__global__ __launch_bounds__(256) void wt_convert_all(const float* __restrict__ W0,
                                                      const float* __restrict__ W1,
                                                      const float* __restrict__ W2,
                                                      const float* __restrict__ W3,
                                                      ushort_t* __restrict__ Wt) {
  __shared__ ushort_t tile[32][33];
  const int z = blockIdx.z, mat = z >> 2, s = z & 3;
  const float* W = (mat == 0) ? W0 : (mat == 1) ? W1 : (mat == 2) ? W2 : W3;
  const float scale = (mat == 0) ? QSC : 1.0f;
  const float* Ws = W + (size_t)s * D_ * D_;
  ushort_t* Wts = Wt + ((size_t)mat * SPLIT_ + s) * D_ * D_;
  const int e0 = blockIdx.x * 32, d0 = blockIdx.y * 32;
  for (int i = threadIdx.y; i < 32; i += 8)
    tile[i][threadIdx.x] = f2bf(Ws[(size_t)(d0 + i) * D_ + e0 + threadIdx.x] * scale);
  __syncthreads();
  for (int i = threadIdx.y; i < 32; i += 8)
    Wts[(size_t)(e0 + i) * D_ + d0 + threadIdx.x] = tile[threadIdx.x][i];
}

// ------------- fused QKV GEMM, 3-deep pipeline, chunk-major LDS -------------
// Q = X@Wq + bq*QSC (bf16 [l][e]), K = X@Wk + bk (bf16 [l][e]), V^T ([e][l]).
// Tile 128m x 64n per matrix, BK=32, 2x2 waves, 3 LDS buffers (60KB -> 2
// blocks/CU; 80KB proved to drop to 1 block, R5). Counted vmcnt(10): the
// two newer stages stay in flight across barriers.
// LDS layout: per 16-row x 32-k window (1024B), slot = chunk*16 + row
// (chunk-major). Fragment reads become base + lane*16 (linear, 2-way-free
// banks) -- the old row-major 64B rows were an 8-way bank conflict
// (SQ_LDS_BANK_CONFLICT 1.09e7/dispatch, ~4 extra cyc per ds_read_b128).
__global__ __launch_bounds__(256) void gemm_qkv(const ushort_t* __restrict__ X,
                                                const ushort_t* __restrict__ Wt,
                                                const float* __restrict__ Bq,
                                                const float* __restrict__ Bk,
                                                const float* __restrict__ Bv,
                                                ushort_t* __restrict__ Qo,
                                                ushort_t* __restrict__ Ko,
                                                ushort_t* __restrict__ Vo) {
  // LDS: As[3][128*32] (24KB) | Bs[3][3][64*32] (36KB) = 60KB; CT overlays.
  __shared__ __attribute__((aligned(16))) ushort_t SH[30720];

  const size_t WT = (size_t)D_ * D_;
  const int xcd = blockIdx.x;
  const int u = blockIdx.y;
  const int bs = xcd + ((u >> 7) << 3);
  const int mn = u & 127;
  const int m0 = (mn & 7) * 128;    // m fastest
  const int n0 = (mn >> 3) * 64;
  const int s = bs & 3;
  const ushort_t* Xb = X + (size_t)bs * (L_ * D_);

  const int t = threadIdx.x;
  const int lane = t & 63;
  const int w = t >> 6;
  const int wm = w >> 1, wn = w & 1;
  const int quad = lane >> 4, cl = lane & 15;

  floatx4 acc[3][4][2];
  floatx4 zero = {0.f, 0.f, 0.f, 0.f};
#pragma unroll
  for (int mt = 0; mt < 3; ++mt)
#pragma unroll
    for (int i = 0; i < 4; ++i)
#pragma unroll
      for (int j = 0; j < 2; ++j) acc[mt][i][j] = zero;

  // chunk-major staging source: thread t writes LDS byte t*16 (linear dest);
  // it must fetch logical (row = (t>>6)*16 + (t&15), k-chunk = (t>>4)&3).
  const int Ra = ((t >> 6) << 4) + (t & 15);
  const int ca = ((t >> 4) & 3) * 8;
  const ushort_t* A0 = Xb + (size_t)(m0 + Ra) * D_ + ca;            // rows 0-63
  const ushort_t* A1 = A0 + (size_t)64 * D_;                        // rows 64-127
  const ushort_t* Bsrc0 = Wt + (0 * SPLIT_ + s) * WT + (size_t)(n0 + Ra) * D_ + ca;
  const ushort_t* Bsrc1 = Wt + (1 * SPLIT_ + s) * WT + (size_t)(n0 + Ra) * D_ + ca;
  const ushort_t* Bsrc2 = Wt + (2 * SPLIT_ + s) * WT + (size_t)(n0 + Ra) * D_ + ca;

  auto STAGE = [&](int buf, int k0) {
    gl2lds16(A0 + k0, &SH[buf * 4096 + t * 8]);
    gl2lds16(A1 + k0, &SH[buf * 4096 + (t + 256) * 8]);
    gl2lds16(Bsrc0 + k0, &SH[12288 + buf * 6144 + 0 * 2048 + t * 8]);
    gl2lds16(Bsrc1 + k0, &SH[12288 + buf * 6144 + 1 * 2048 + t * 8]);
    gl2lds16(Bsrc2 + k0, &SH[12288 + buf * 6144 + 2 * 2048 + t * 8]);
  };

  // fragment reads: window base + lane*16B (linear; A windows are 16 rows)
  auto COMPUTE = [&](int buf) {
    const ushort_t* Ab = &SH[buf * 4096];
    const ushort_t* Bb = &SH[12288 + buf * 6144];
    short8 a[4];
#pragma unroll
    for (int i = 0; i < 4; ++i)
      a[i] = *(const short8*)&Ab[(wm * 4 + i) * 512 + lane * 8];
#pragma unroll
    for (int mt = 0; mt < 3; ++mt) {
      const ushort_t* Bm = Bb + mt * 2048;
      const short8 b0 = *(const short8*)&Bm[(wn * 2) * 512 + lane * 8];
      const short8 b1 = *(const short8*)&Bm[(wn * 2 + 1) * 512 + lane * 8];
#pragma unroll
      for (int i = 0; i < 4; ++i) {
        acc[mt][i][0] = __builtin_amdgcn_mfma_f32_16x16x32_bf16(a[i], b0, acc[mt][i][0], 0, 0, 0);
        acc[mt][i][1] = __builtin_amdgcn_mfma_f32_16x16x32_bf16(a[i], b1, acc[mt][i][1], 0, 0, 0);
      }
    }
  };

  STAGE(0, 0);
  STAGE(1, 32);
#define QKV_STEP(SB, CB, KS)                              \
  STAGE(SB, (KS)*32);                                     \
  asm volatile("s_waitcnt vmcnt(10)" ::: "memory");       \
  wave_barrier();                                         \
  COMPUTE(CB);                                            \
  wave_barrier();
  for (int k3 = 0; k3 < 30; k3 += 3) {
    QKV_STEP(2, 0, k3 + 2)
    QKV_STEP(0, 1, k3 + 3)
    QKV_STEP(1, 2, k3 + 4)
  }
#undef QKV_STEP
  asm volatile("s_waitcnt vmcnt(5)" ::: "memory");
  wave_barrier();
  COMPUTE(0);                     // kstep 30 -> buf 0
  wave_barrier();
  asm volatile("s_waitcnt vmcnt(0)" ::: "memory");
  wave_barrier();
  COMPUTE(1);                     // kstep 31 -> buf 1

  // ---- epilogue: LDS-staged coalesced stores, one matrix at a time ----
  __syncthreads();                 // nothing in flight; free SH for CT
  ushort_t* CT = SH;

#pragma unroll
  for (int mt = 0; mt < 2; ++mt) {   // Q, K : bf16 [l][e]
    const float* bp = (mt == 0) ? Bq : Bk;
    ushort_t* Og = (mt == 0) ? Qo : Ko;
    const float bscale = (mt == 0) ? QSC : 1.0f;
    float bvj[2];
#pragma unroll
    for (int j = 0; j < 2; ++j)
      bvj[j] = bp[s * D_ + n0 + wn * 32 + j * 16 + cl] * bscale;
#pragma unroll
    for (int i = 0; i < 4; ++i)
#pragma unroll
      for (int j = 0; j < 2; ++j)
#pragma unroll
        for (int r = 0; r < 4; ++r) {
          const int row = wm * 64 + i * 16 + quad * 4 + r;
          const int col = wn * 32 + j * 16 + cl;
          const int ch = col >> 3, off = col & 7;
          CT[row * 64 + ((ch ^ (row & 7)) << 3) + off] = f2bf(acc[mt][i][j][r] + bvj[j]);
        }
    __syncthreads();
#pragma unroll
    for (int pass = 0; pass < 4; ++pass) {
      const int row = pass * 32 + (t >> 3);
      const int ck = t & 7;
      const short8 v = *(const short8*)&CT[row * 64 + ((ck ^ (row & 7)) << 3)];
      *(short8*)(Og + (size_t)bs * (L_ * D_) + (size_t)(m0 + row) * D_ + n0 + ck * 8) = v;
    }
    __syncthreads();
  }

  {  // V : bf16 transposed [e][l]
    float bvj[2];
#pragma unroll
    for (int j = 0; j < 2; ++j)
      bvj[j] = Bv[s * D_ + n0 + wn * 32 + j * 16 + cl];
#pragma unroll
    for (int i = 0; i < 4; ++i)
#pragma unroll
      for (int j = 0; j < 2; ++j)
#pragma unroll
        for (int r = 0; r < 4; ++r) {
          const int row = wn * 32 + j * 16 + cl;            // e (64)
          const int col = wm * 64 + i * 16 + quad * 4 + r;  // l (128)
          const int ch = col >> 3, off = col & 7;
          CT[row * 128 + ((ch ^ (row & 15)) << 3) + off] = f2bf(acc[2][i][j][r] + bvj[j]);
        }
    __syncthreads();
#pragma unroll
    for (int pass = 0; pass < 4; ++pass) {
      const int row = pass * 16 + (t >> 4);
      const int ck = t & 15;
      const short8 v = *(const short8*)&CT[row * 128 + ((ck ^ (row & 15)) << 3)];
      *(short8*)(Vo + (size_t)bs * (L_ * D_) + (size_t)(n0 + row) * L_ + m0 + ck * 8) = v;
    }
  }
}

// ------------- O-projection GEMM, 3-deep pipeline, chunk-major LDS ----------
// C = Ob @ Wo + bo, fp32 [l][e] direct stores. 128x128 tile, BK=32,
// 3 LDS buffers (48KB), counted vmcnt(8). Same chunk-major layout as qkv.
__global__ __launch_bounds__(256) void gemm_o(const ushort_t* __restrict__ X,
                                              const ushort_t* __restrict__ Wt,
                                              const float* __restrict__ bias,
                                              float* __restrict__ C) {
  __shared__ __attribute__((aligned(16))) ushort_t SH[24576];  // A[3]|B[3]

  const int xcd = blockIdx.x;
  const int u = blockIdx.y;
  const int bs = xcd + ((u >> 6) << 3);
  const int mn = u & 63;
  const int m0 = (mn >> 3) * 128;
  const int n0 = (mn & 7) * 128;
  const int s = bs & 3;
  const ushort_t* Xb = X + (size_t)bs * (L_ * D_);
  const ushort_t* Wts = Wt + (size_t)s * (D_ * D_);

  const int t = threadIdx.x;
  const int lane = t & 63;
  const int w = t >> 6;
  const int wm = w >> 1, wn = w & 1;
  const int quad = lane >> 4, cl = lane & 15;

  floatx4 acc[4][4];
  floatx4 zero = {0.f, 0.f, 0.f, 0.f};
#pragma unroll
  for (int i = 0; i < 4; ++i)
#pragma unroll
    for (int j = 0; j < 4; ++j) acc[i][j] = zero;

  const int Ra = ((t >> 6) << 4) + (t & 15);
  const int ca = ((t >> 4) & 3) * 8;
  const ushort_t* A0 = Xb + (size_t)(m0 + Ra) * D_ + ca;
  const ushort_t* A1 = A0 + (size_t)64 * D_;
  const ushort_t* B0 = Wts + (size_t)(n0 + Ra) * D_ + ca;
  const ushort_t* B1 = B0 + (size_t)64 * D_;

  auto STAGE = [&](int buf, int k0) {
    gl2lds16(A0 + k0, &SH[buf * 4096 + t * 8]);
    gl2lds16(A1 + k0, &SH[buf * 4096 + (t + 256) * 8]);
    gl2lds16(B0 + k0, &SH[12288 + buf * 4096 + t * 8]);
    gl2lds16(B1 + k0, &SH[12288 + buf * 4096 + (t + 256) * 8]);
  };

  auto COMPUTE = [&](int buf) {
    const ushort_t* As = &SH[buf * 4096];
    const ushort_t* Bs = &SH[12288 + buf * 4096];
    short8 a[4], b[4];
#pragma unroll
    for (int i = 0; i < 4; ++i)
      a[i] = *(const short8*)&As[(wm * 4 + i) * 512 + lane * 8];
#pragma unroll
    for (int j = 0; j < 4; ++j)
      b[j] = *(const short8*)&Bs[(wn * 4 + j) * 512 + lane * 8];
#pragma unroll
    for (int i = 0; i < 4; ++i)
#pragma unroll
      for (int j = 0; j < 4; ++j)
        acc[i][j] = __builtin_amdgcn_mfma_f32_16x16x32_bf16(a[i], b[j], acc[i][j], 0, 0, 0);
  };

  STAGE(0, 0);
  STAGE(1, 32);
#define O_STEP(SB, CB, KS)                                \
  STAGE(SB, (KS)*32);                                     \
  asm volatile("s_waitcnt vmcnt(8)" ::: "memory");        \
  wave_barrier();                                         \
  COMPUTE(CB);                                            \
  wave_barrier();
  for (int k3 = 0; k3 < 30; k3 += 3) {
    O_STEP(2, 0, k3 + 2)
    O_STEP(0, 1, k3 + 3)
    O_STEP(1, 2, k3 + 4)
  }
#undef O_STEP
  asm volatile("s_waitcnt vmcnt(4)" ::: "memory");
  wave_barrier();
  COMPUTE(0);                     // kstep 30
  wave_barrier();
  asm volatile("s_waitcnt vmcnt(0)" ::: "memory");
  wave_barrier();
  COMPUTE(1);                     // kstep 31

  // bias per output column (C/D layout: col=lane&15, row=quad*4+reg)
  float bvj[4];
#pragma unroll
  for (int j = 0; j < 4; ++j)
    bvj[j] = bias[s * D_ + n0 + wn * 64 + j * 16 + cl];

#pragma unroll
  for (int j = 0; j < 4; ++j) {
    const int col = n0 + wn * 64 + j * 16 + cl;
#pragma unroll
    for (int i = 0; i < 4; ++i) {
      const int rb = m0 + wm * 64 + i * 16 + quad * 4;
      float* Cf = C + (size_t)bs * (L_ * D_) + (size_t)rb * D_ + col;
#pragma unroll
      for (int r = 0; r < 4; ++r) Cf[(size_t)r * D_] = acc[i][j][r] + bvj[j];
    }
  }
}

// ------------- attention tile step (per-wave, no barrier) -------------------
__device__ __forceinline__ void attn_step(const ushort_t* __restrict__ Kbuf,
                                          const ushort_t* __restrict__ Vbuf,
                                          ushort_t* __restrict__ PTw,
                                          const short8 qa0, const short8 qa1,
                                          floatx4 (&o)[4], float& m_i, float& l_i,
                                          const bool diag, const int w,
                                          const int quad, const int cl) {
  floatx4 zero = {0.f, 0.f, 0.f, 0.f};
  const int sw0 = (quad ^ (cl & 7)) * 8;
  const int sw1 = ((4 + quad) ^ (cl & 7)) * 8;

  floatx4 st[4];
  __builtin_amdgcn_s_setprio(1);
#pragma unroll
  for (int j = 0; j < 4; ++j) {
    const int row = (j * 16 + cl) * 64;
    const short8 ka0 = *(const short8*)&Kbuf[row + sw0];
    const short8 ka1 = *(const short8*)&Kbuf[row + sw1];
    floatx4 z = zero;
    z = __builtin_amdgcn_mfma_f32_16x16x32_bf16(ka0, qa0, z, 0, 0, 0);
    z = __builtin_amdgcn_mfma_f32_16x16x32_bf16(ka1, qa1, z, 0, 0, 0);
    st[j] = z;
  }
  __builtin_amdgcn_s_setprio(0);

  if (diag) {  // causal mask on diagonal tile (kv_local > q_local)
    const int ql = w * 16 + cl;
#pragma unroll
    for (int j = 0; j < 4; ++j)
#pragma unroll
      for (int r = 0; r < 4; ++r)
        if (j * 16 + quad * 4 + r > ql) st[j][r] = -1e30f;
  }

  // per-lane max over 16 kv values (v_max3 tree) + 2 shfls across quads
  float t0 = fmax3(st[0][0], st[0][1], st[0][2]);
  float t1 = fmax3(st[0][3], st[1][0], st[1][1]);
  float t2 = fmax3(st[1][2], st[1][3], st[2][0]);
  float t3 = fmax3(st[2][1], st[2][2], st[2][3]);
  float t4 = fmax3(st[3][0], st[3][1], st[3][2]);
  float tm = fmaxf(fmax3(t0, t1, t2), fmax3(t3, t4, st[3][3]));
  tm = fmaxf(tm, __shfl_xor(tm, 16, 64));
  tm = fmaxf(tm, __shfl_xor(tm, 32, 64));
  const float mnew = fmaxf(m_i, tm);
  const float alpha = exp2f_fast(m_i - mnew);
  m_i = mnew;

  float tsv = 0.f;
#pragma unroll
  for (int j = 0; j < 4; ++j)
#pragma unroll
    for (int r = 0; r < 4; ++r) {
      st[j][r] = exp2f_fast(st[j][r] - mnew);
      tsv += st[j][r];
    }
  tsv += __shfl_xor(tsv, 16, 64);
  tsv += __shfl_xor(tsv, 32, 64);
  l_i = l_i * alpha + tsv;

  // P^T pairs -> per-wave LDS (b32 writes)
#pragma unroll
  for (int j = 0; j < 4; ++j) {
    const int base = cl * 72 + j * 16 + quad * 4;
    *(uint32_t*)&PTw[base] = pack_bf_trunc(st[j][0], st[j][1]);
    *(uint32_t*)&PTw[base + 2] = pack_bf_trunc(st[j][2], st[j][3]);
  }

#pragma unroll
  for (int j = 0; j < 4; ++j)
#pragma unroll
    for (int r = 0; r < 4; ++r) o[j][r] *= alpha;

  // O^T += V^T P^T
  const short8 pb0 = *(const short8*)&PTw[cl * 72 + quad * 8];
  const short8 pb1 = *(const short8*)&PTw[cl * 72 + 32 + quad * 8];
  __builtin_amdgcn_s_setprio(1);
#pragma unroll
  for (int j = 0; j < 4; ++j) {
    const int row = (j * 16 + cl) * 64;
    const short8 va0 = *(const short8*)&Vbuf[row + sw0];
    const short8 va1 = *(const short8*)&Vbuf[row + sw1];
    o[j] = __builtin_amdgcn_mfma_f32_16x16x32_bf16(va0, pb0, o[j], 0, 0, 0);
    o[j] = __builtin_amdgcn_mfma_f32_16x16x32_bf16(va1, pb1, o[j], 0, 0, 0);
  }
  __builtin_amdgcn_s_setprio(0);
}

__device__ __forceinline__ void attn_store(ushort_t* __restrict__ O, size_t act_base,
                                           int qt, int h, const floatx4 (&o)[4],
                                           float l_i, int w, int quad, int cl) {
  const float inv = 1.0f / l_i;
  ushort_t* Orow = O + act_base + (size_t)(qt * 64 + w * 16 + cl) * D_ + h * DK_;
#pragma unroll
  for (int j = 0; j < 4; ++j) {
    ushortx4 pk;
#pragma unroll
    for (int r = 0; r < 4; ++r) pk[r] = f2bf(o[j][r] * inv);
    *(ushortx4*)(Orow + j * 16 + quad * 4) = pk;
  }
}

// ------------- flash attention (dual-Q shared-KV) ---------------------------
__global__ __launch_bounds__(256) void attn_kernel(const ushort_t* __restrict__ Q,
                                                   const ushort_t* __restrict__ K,
                                                   const ushort_t* __restrict__ Vt,
                                                   ushort_t* __restrict__ O) {
  __shared__ __attribute__((aligned(16))) ushort_t Ks[2][64 * 64];   // [kv][dk] swz
  __shared__ __attribute__((aligned(16))) ushort_t Vts[2][64 * 64];  // [dk][kv] swz
  __shared__ __attribute__((aligned(16))) ushort_t PT[8][1152];      // per-wave A/B

  const int p = blockIdx.x, h = blockIdx.y, bs = blockIdx.z;
  const int t = threadIdx.x, lane = t & 63, w = t >> 6;
  const int quad = lane >> 4, cl = lane & 15;
  const size_t act_base = (size_t)bs * (L_ * D_);
  const int qtA = p, qtB = 15 - p;
  const int NIT = 16 - p;  // kv tiles 0..15-p

  const int cA = t, cB = t + 256;
  const int rA = cA >> 3, ccA = ((cA & 7) ^ (rA & 7)) * 8;
  const int rB = cB >> 3, ccB = ((cB & 7) ^ (rB & 7)) * 8;

  const ushort_t* pKA = K + act_base + (size_t)rA * D_ + h * DK_ + ccA;
  const ushort_t* pKB = K + act_base + (size_t)rB * D_ + h * DK_ + ccB;
  const ushort_t* pVA = Vt + act_base + (size_t)(h * DK_ + rA) * L_ + ccA;
  const ushort_t* pVB = Vt + act_base + (size_t)(h * DK_ + rB) * L_ + ccB;
  const size_t kstep = (size_t)64 * D_, vstep = 64;

  floatx4 zero = {0.f, 0.f, 0.f, 0.f};

  // Q fragments for both tiles (B-operand: lane=q-row, k contiguous)
  const ushort_t* QpA = Q + act_base + (size_t)(qtA * 64 + w * 16 + cl) * D_ + h * DK_ + quad * 8;
  const ushort_t* QpB = Q + act_base + (size_t)(qtB * 64 + w * 16 + cl) * D_ + h * DK_ + quad * 8;
  const short8 qaA0 = *(const short8*)QpA;
  const short8 qaA1 = *(const short8*)(QpA + 32);
  const short8 qaB0 = *(const short8*)QpB;
  const short8 qaB1 = *(const short8*)(QpB + 32);

  floatx4 oA[4], oB[4];
#pragma unroll
  for (int j = 0; j < 4; ++j) { oA[j] = zero; oB[j] = zero; }
  float mA = -3.0e38f, lA = 0.f, mB = -3.0e38f, lB = 0.f;

  // issue kv=0 into buf 0
  gl2lds16(pKA, &Ks[0][cA * 8]);
  gl2lds16(pKB, &Ks[0][cB * 8]);
  gl2lds16(pVA, &Vts[0][cA * 8]);
  gl2lds16(pVB, &Vts[0][cB * 8]);

  for (int kv = 0; kv < NIT; ++kv) {
    __syncthreads();  // drains buf[kv&1] loads; prior reads of other buf done
    if (kv + 1 < NIT) {
      pKA += kstep; pKB += kstep; pVA += vstep; pVB += vstep;
      const int nb = (kv + 1) & 1;
      gl2lds16(pKA, &Ks[nb][cA * 8]);
      gl2lds16(pKB, &Ks[nb][cB * 8]);
      gl2lds16(pVA, &Vts[nb][cA * 8]);
      gl2lds16(pVB, &Vts[nb][cB * 8]);
    }
    const int buf = kv & 1;

    if (kv <= p) {
      attn_step(Ks[buf], Vts[buf], PT[w], qaA0, qaA1, oA, mA, lA,
                kv == p, w, quad, cl);
      if (kv == p) attn_store(O, act_base, qtA, h, oA, lA, w, quad, cl);
    }
    attn_step(Ks[buf], Vts[buf], PT[w + 4], qaB0, qaB1, oB, mB, lB,
              kv == NIT - 1, w, quad, cl);
  }
  attn_store(O, act_base, qtB, h, oB, lB, w, quad, cl);
}

extern "C" void kernel_launch(void* const* d_in, const int* in_sizes, int n_in,
                              void* d_out, int out_size, void* d_ws, size_t ws_size,
                              hipStream_t stream) {
  const float* x  = (const float*)d_in[0];
  const float* Wq = (const float*)d_in[1];
  const float* Wk = (const float*)d_in[2];
  const float* Wv = (const float*)d_in[3];
  const float* Wo = (const float*)d_in[4];
  const float* bq = (const float*)d_in[5];
  const float* bk = (const float*)d_in[6];
  const float* bv = (const float*)d_in[7];
  const float* bo = (const float*)d_in[8];

  const size_t WT_SZ = (size_t)SPLIT_ * D_ * D_;  // 4 Mi elements
  const size_t ACT_SZ = (size_t)B_ * SEQ_ * D_;   // 16 Mi elements

  // ws layout (bf16): xbf[16Mi] | wt[4][4Mi] | Vt[16Mi]  => 96 MiB total
  ushort_t* ws0 = (ushort_t*)d_ws;
  ushort_t* xbf = ws0;
  ushort_t* wtall = xbf + ACT_SZ;
  ushort_t* wto = wtall + 3 * WT_SZ;
  ushort_t* Vtb = wtall + 4 * WT_SZ;
  // d_out (16Mi fp32 = 64 MiB) doubles as Q/K bf16 scratch until the final GEMM
  ushort_t* Qb = (ushort_t*)d_out;
  ushort_t* Kb = Qb + ACT_SZ;
  ushort_t* Ob = xbf;  // attention output reuses xbf (x dead after V projection)

  convert_x<<<ACT_SZ / 1024, 256, 0, stream>>>(x, xbf);
  wt_convert_all<<<dim3(32, 32, 16), dim3(32, 8, 1), 0, stream>>>(Wq, Wk, Wv, Wo, wtall);

  // fused Q/K/V projection: one launch, shared A, 3-deep counted-vmcnt pipeline
  gemm_qkv<<<dim3(8, 256, 1), dim3(256, 1, 1), 0, stream>>>(
      xbf, wtall, bq, bk, bv, Qb, Kb, Vtb);

  dim3 ag(8, 16, 16);
  attn_kernel<<<ag, dim3(256, 1, 1), 0, stream>>>(Qb, Kb, Vtb, Ob);

  gemm_o<<<dim3(8, 128, 1), dim3(256, 1, 1), 0, stream>>>(Ob, wto, bo, (float*)d_out);
}

// Round 7
// 418.885 us; speedup vs baseline: 1.1577x; 1.1577x over previous
//
#include <hip/hip_runtime.h>
#include <stdint.h>

#define H_ 16
#define D_ 1024
#define SPLIT_ 4
#define DK_ 64
#define B_ 4
#define SEQ_ 4096
#define L_ 1024

// 0.125 * log2(e): folded into Wq/bq so attn softmax runs in exp2 domain.
#define QSC 0.18033688f

typedef unsigned short ushort_t;
typedef __attribute__((ext_vector_type(8))) short short8;
typedef __attribute__((ext_vector_type(4))) float floatx4;
typedef __attribute__((ext_vector_type(4))) unsigned short ushortx4;

__device__ __forceinline__ ushort_t f2bf(float f) {   // RNE
  union { float f; unsigned u; } cv; cv.f = f;
  unsigned u = cv.u;
  return (ushort_t)((u + 0x7fffu + ((u >> 16) & 1u)) >> 16);
}

// pack two floats -> bf16x2 (truncating) in one v_perm_b32
__device__ __forceinline__ uint32_t pack_bf_trunc(float x, float y) {
#if __has_builtin(__builtin_amdgcn_perm)
  return __builtin_amdgcn_perm(__float_as_uint(y), __float_as_uint(x), 0x07060302u);
#else
  return (__float_as_uint(y) & 0xffff0000u) | (__float_as_uint(x) >> 16);
#endif
}

__device__ __forceinline__ float exp2f_fast(float x) {
#if __has_builtin(__builtin_amdgcn_exp2f)
  return __builtin_amdgcn_exp2f(x);
#else
  return exp2f(x);
#endif
}

__device__ __forceinline__ float fmax3(float a, float b, float c) {
  return fmaxf(fmaxf(a, b), c);   // clang fuses to v_max3_f32
}

// async 16B global->LDS (dest must be wave-uniform base + lane*16)
__device__ __forceinline__ void gl2lds16(const ushort_t* g, ushort_t* l) {
  __builtin_amdgcn_global_load_lds(
      (const __attribute__((address_space(1))) uint32_t*)g,
      (__attribute__((address_space(3))) uint32_t*)l, 16, 0, 0);
}

// raw workgroup barrier WITHOUT the compiler's vmcnt(0) drain.
__device__ __forceinline__ void wave_barrier() {
  asm volatile("" ::: "memory");
  __builtin_amdgcn_s_barrier();
  asm volatile("" ::: "memory");
}

// ------------- x: fp32 -> bf16 (contiguous) ---------------------------------
__global__ __launch_bounds__(256) void convert_x(const float* __restrict__ X,
                                                 ushort_t* __restrict__ Y) {
  const int i = blockIdx.x * 256 + threadIdx.x;
  const float4 v = ((const float4*)X)[i];
  ushortx4 o;
  o[0] = f2bf(v.x); o[1] = f2bf(v.y); o[2] = f2bf(v.z); o[3] = f2bf(v.w);
  ((ushortx4*)Y)[i] = o;
}

// ------------- all 4 weights: W[s][d][e] fp32 -> Wt[mat][s][e][d] bf16 ------
__global__ __launch_bounds__(256) void wt_convert_all(const float* __restrict__ W0,
                                                      const float* __restrict__ W1,
                                                      const float* __restrict__ W2,
                                                      const float* __restrict__ W3,
                                                      ushort_t* __restrict__ Wt) {
  __shared__ ushort_t tile[32][33];
  const int z = blockIdx.z, mat = z >> 2, s = z & 3;
  const float* W = (mat == 0) ? W0 : (mat == 1) ? W1 : (mat == 2) ? W2 : W3;
  const float scale = (mat == 0) ? QSC : 1.0f;
  const float* Ws = W + (size_t)s * D_ * D_;
  ushort_t* Wts = Wt + ((size_t)mat * SPLIT_ + s) * D_ * D_;
  const int e0 = blockIdx.x * 32, d0 = blockIdx.y * 32;
  for (int i = threadIdx.y; i < 32; i += 8)
    tile[i][threadIdx.x] = f2bf(Ws[(size_t)(d0 + i) * D_ + e0 + threadIdx.x] * scale);
  __syncthreads();
  for (int i = threadIdx.y; i < 32; i += 8)
    Wts[(size_t)(e0 + i) * D_ + d0 + threadIdx.x] = tile[threadIdx.x][i];
}

// ---- LDS tile mapping (both GEMMs) -----------------------------------------
// Per 16-row x 32-k window (64 granules of 16B, 1024B):
//   slot p (0-15) holds row rho(p) = ((p&3)<<2)|(p>>2)   (involution);
//   granule g of slot p holds k-chunk g ^ ((p>>2)&3).
// STAGE thread t: p=(t>>2)&15, g=t&3 -> fetch row rho(p), chunk g^((p>>2)&3):
//   4-lane groups fetch one dense 64B row -> global coalescing preserved
//   (chunk-major's 2KB-stride scatter was the R6 regression: 174us).
// READ lane (cl,quad): granule 4*rho(cl) + (quad^(cl&3)); quarter-wave
//   bank residues 4((cl>>2)&1) + (quad^(cl&3)) = all 8 twice -> 2-way (free).
//   (Old row-major XOR gave 4 residues -> 4-way, 1.09e7 conflict cyc.)

// ------------- fused QKV GEMM, 3-deep pipeline ------------------------------
// Q = X@Wq + bq*QSC (bf16 [l][e]), K = X@Wk + bk (bf16 [l][e]), V^T ([e][l]).
// Tile 128m x 64n per matrix, BK=32, 2x2 waves, 3 LDS buffers (60KB -> 2
// blocks/CU; 80KB drops to 1 block, R5). Counted vmcnt(10).
__global__ __launch_bounds__(256) void gemm_qkv(const ushort_t* __restrict__ X,
                                                const ushort_t* __restrict__ Wt,
                                                const float* __restrict__ Bq,
                                                const float* __restrict__ Bk,
                                                const float* __restrict__ Bv,
                                                ushort_t* __restrict__ Qo,
                                                ushort_t* __restrict__ Ko,
                                                ushort_t* __restrict__ Vo) {
  // LDS: As[3][128*32] (24KB) | Bs[3][3][64*32] (36KB) = 60KB; CT overlays.
  __shared__ __attribute__((aligned(16))) ushort_t SH[30720];

  const size_t WT = (size_t)D_ * D_;
  const int xcd = blockIdx.x;
  const int u = blockIdx.y;
  const int bs = xcd + ((u >> 7) << 3);
  const int mn = u & 127;
  const int m0 = (mn & 7) * 128;    // m fastest
  const int n0 = (mn >> 3) * 64;
  const int s = bs & 3;
  const ushort_t* Xb = X + (size_t)bs * (L_ * D_);

  const int t = threadIdx.x;
  const int lane = t & 63;
  const int w = t >> 6;
  const int wm = w >> 1, wn = w & 1;
  const int quad = lane >> 4, cl = lane & 15;

  floatx4 acc[3][4][2];
  floatx4 zero = {0.f, 0.f, 0.f, 0.f};
#pragma unroll
  for (int mt = 0; mt < 3; ++mt)
#pragma unroll
    for (int i = 0; i < 4; ++i)
#pragma unroll
      for (int j = 0; j < 2; ++j) acc[mt][i][j] = zero;

  // staging source per mapping above
  const int tp = (t >> 2) & 15;                         // slot
  const int Ra = ((t >> 6) << 4) + (((tp & 3) << 2) | (tp >> 2));  // row
  const int ca = ((t & 3) ^ ((tp >> 2) & 3)) * 8;                  // chunk elems
  const ushort_t* A0 = Xb + (size_t)(m0 + Ra) * D_ + ca;           // rows 0-63
  const ushort_t* A1 = A0 + (size_t)64 * D_;                       // rows 64-127
  const ushort_t* Bsrc0 = Wt + (0 * SPLIT_ + s) * WT + (size_t)(n0 + Ra) * D_ + ca;
  const ushort_t* Bsrc1 = Wt + (1 * SPLIT_ + s) * WT + (size_t)(n0 + Ra) * D_ + ca;
  const ushort_t* Bsrc2 = Wt + (2 * SPLIT_ + s) * WT + (size_t)(n0 + Ra) * D_ + ca;

  auto STAGE = [&](int buf, int k0) {
    gl2lds16(A0 + k0, &SH[buf * 4096 + t * 8]);
    gl2lds16(A1 + k0, &SH[buf * 4096 + (t + 256) * 8]);
    gl2lds16(Bsrc0 + k0, &SH[12288 + buf * 6144 + 0 * 2048 + t * 8]);
    gl2lds16(Bsrc1 + k0, &SH[12288 + buf * 6144 + 1 * 2048 + t * 8]);
    gl2lds16(Bsrc2 + k0, &SH[12288 + buf * 6144 + 2 * 2048 + t * 8]);
  };

  // fragment reads: window*512 + rsel*8 ushorts
  const int rsel = ((cl & 3) << 4) + ((cl >> 2) << 2) + (quad ^ (cl & 3));
  auto COMPUTE = [&](int buf) {
    const ushort_t* Ab = &SH[buf * 4096];
    const ushort_t* Bb = &SH[12288 + buf * 6144];
    short8 a[4];
#pragma unroll
    for (int i = 0; i < 4; ++i)
      a[i] = *(const short8*)&Ab[(wm * 4 + i) * 512 + rsel * 8];
#pragma unroll
    for (int mt = 0; mt < 3; ++mt) {
      const ushort_t* Bm = Bb + mt * 2048;
      const short8 b0 = *(const short8*)&Bm[(wn * 2) * 512 + rsel * 8];
      const short8 b1 = *(const short8*)&Bm[(wn * 2 + 1) * 512 + rsel * 8];
#pragma unroll
      for (int i = 0; i < 4; ++i) {
        acc[mt][i][0] = __builtin_amdgcn_mfma_f32_16x16x32_bf16(a[i], b0, acc[mt][i][0], 0, 0, 0);
        acc[mt][i][1] = __builtin_amdgcn_mfma_f32_16x16x32_bf16(a[i], b1, acc[mt][i][1], 0, 0, 0);
      }
    }
  };

  STAGE(0, 0);
  STAGE(1, 32);
#define QKV_STEP(SB, CB, KS)                              \
  STAGE(SB, (KS)*32);                                     \
  asm volatile("s_waitcnt vmcnt(10)" ::: "memory");       \
  wave_barrier();                                         \
  COMPUTE(CB);                                            \
  wave_barrier();
  for (int k3 = 0; k3 < 30; k3 += 3) {
    QKV_STEP(2, 0, k3 + 2)
    QKV_STEP(0, 1, k3 + 3)
    QKV_STEP(1, 2, k3 + 4)
  }
#undef QKV_STEP
  asm volatile("s_waitcnt vmcnt(5)" ::: "memory");
  wave_barrier();
  COMPUTE(0);                     // kstep 30 -> buf 0
  wave_barrier();
  asm volatile("s_waitcnt vmcnt(0)" ::: "memory");
  wave_barrier();
  COMPUTE(1);                     // kstep 31 -> buf 1

  // ---- epilogue: LDS-staged coalesced stores, one matrix at a time ----
  __syncthreads();                 // nothing in flight; free SH for CT
  ushort_t* CT = SH;

#pragma unroll
  for (int mt = 0; mt < 2; ++mt) {   // Q, K : bf16 [l][e]
    const float* bp = (mt == 0) ? Bq : Bk;
    ushort_t* Og = (mt == 0) ? Qo : Ko;
    const float bscale = (mt == 0) ? QSC : 1.0f;
    float bvj[2];
#pragma unroll
    for (int j = 0; j < 2; ++j)
      bvj[j] = bp[s * D_ + n0 + wn * 32 + j * 16 + cl] * bscale;
#pragma unroll
    for (int i = 0; i < 4; ++i)
#pragma unroll
      for (int j = 0; j < 2; ++j)
#pragma unroll
        for (int r = 0; r < 4; ++r) {
          const int row = wm * 64 + i * 16 + quad * 4 + r;
          const int col = wn * 32 + j * 16 + cl;
          const int ch = col >> 3, off = col & 7;
          CT[row * 64 + ((ch ^ (row & 7)) << 3) + off] = f2bf(acc[mt][i][j][r] + bvj[j]);
        }
    __syncthreads();
#pragma unroll
    for (int pass = 0; pass < 4; ++pass) {
      const int row = pass * 32 + (t >> 3);
      const int ck = t & 7;
      const short8 v = *(const short8*)&CT[row * 64 + ((ck ^ (row & 7)) << 3)];
      *(short8*)(Og + (size_t)bs * (L_ * D_) + (size_t)(m0 + row) * D_ + n0 + ck * 8) = v;
    }
    __syncthreads();
  }

  {  // V : bf16 transposed [e][l]
    float bvj[2];
#pragma unroll
    for (int j = 0; j < 2; ++j)
      bvj[j] = Bv[s * D_ + n0 + wn * 32 + j * 16 + cl];
#pragma unroll
    for (int i = 0; i < 4; ++i)
#pragma unroll
      for (int j = 0; j < 2; ++j)
#pragma unroll
        for (int r = 0; r < 4; ++r) {
          const int row = wn * 32 + j * 16 + cl;            // e (64)
          const int col = wm * 64 + i * 16 + quad * 4 + r;  // l (128)
          const int ch = col >> 3, off = col & 7;
          CT[row * 128 + ((ch ^ (row & 15)) << 3) + off] = f2bf(acc[2][i][j][r] + bvj[j]);
        }
    __syncthreads();
#pragma unroll
    for (int pass = 0; pass < 4; ++pass) {
      const int row = pass * 16 + (t >> 4);
      const int ck = t & 15;
      const short8 v = *(const short8*)&CT[row * 128 + ((ck ^ (row & 15)) << 3)];
      *(short8*)(Vo + (size_t)bs * (L_ * D_) + (size_t)(n0 + row) * L_ + m0 + ck * 8) = v;
    }
  }
}

// ------------- O-projection GEMM, 3-deep pipeline ---------------------------
// C = Ob @ Wo + bo, fp32 [l][e] direct stores. 128x128 tile, BK=32,
// 3 LDS buffers (48KB), counted vmcnt(8). Same LDS mapping as gemm_qkv.
__global__ __launch_bounds__(256) void gemm_o(const ushort_t* __restrict__ X,
                                              const ushort_t* __restrict__ Wt,
                                              const float* __restrict__ bias,
                                              float* __restrict__ C) {
  __shared__ __attribute__((aligned(16))) ushort_t SH[24576];  // A[3]|B[3]

  const int xcd = blockIdx.x;
  const int u = blockIdx.y;
  const int bs = xcd + ((u >> 6) << 3);
  const int mn = u & 63;
  const int m0 = (mn >> 3) * 128;
  const int n0 = (mn & 7) * 128;
  const int s = bs & 3;
  const ushort_t* Xb = X + (size_t)bs * (L_ * D_);
  const ushort_t* Wts = Wt + (size_t)s * (D_ * D_);

  const int t = threadIdx.x;
  const int lane = t & 63;
  const int w = t >> 6;
  const int wm = w >> 1, wn = w & 1;
  const int quad = lane >> 4, cl = lane & 15;

  floatx4 acc[4][4];
  floatx4 zero = {0.f, 0.f, 0.f, 0.f};
#pragma unroll
  for (int i = 0; i < 4; ++i)
#pragma unroll
    for (int j = 0; j < 4; ++j) acc[i][j] = zero;

  const int tp = (t >> 2) & 15;
  const int Ra = ((t >> 6) << 4) + (((tp & 3) << 2) | (tp >> 2));
  const int ca = ((t & 3) ^ ((tp >> 2) & 3)) * 8;
  const ushort_t* A0 = Xb + (size_t)(m0 + Ra) * D_ + ca;
  const ushort_t* A1 = A0 + (size_t)64 * D_;
  const ushort_t* B0 = Wts + (size_t)(n0 + Ra) * D_ + ca;
  const ushort_t* B1 = B0 + (size_t)64 * D_;

  auto STAGE = [&](int buf, int k0) {
    gl2lds16(A0 + k0, &SH[buf * 4096 + t * 8]);
    gl2lds16(A1 + k0, &SH[buf * 4096 + (t + 256) * 8]);
    gl2lds16(B0 + k0, &SH[12288 + buf * 4096 + t * 8]);
    gl2lds16(B1 + k0, &SH[12288 + buf * 4096 + (t + 256) * 8]);
  };

  const int rsel = ((cl & 3) << 4) + ((cl >> 2) << 2) + (quad ^ (cl & 3));
  auto COMPUTE = [&](int buf) {
    const ushort_t* As = &SH[buf * 4096];
    const ushort_t* Bs = &SH[12288 + buf * 4096];
    short8 a[4], b[4];
#pragma unroll
    for (int i = 0; i < 4; ++i)
      a[i] = *(const short8*)&As[(wm * 4 + i) * 512 + rsel * 8];
#pragma unroll
    for (int j = 0; j < 4; ++j)
      b[j] = *(const short8*)&Bs[(wn * 4 + j) * 512 + rsel * 8];
#pragma unroll
    for (int i = 0; i < 4; ++i)
#pragma unroll
      for (int j = 0; j < 4; ++j)
        acc[i][j] = __builtin_amdgcn_mfma_f32_16x16x32_bf16(a[i], b[j], acc[i][j], 0, 0, 0);
  };

  STAGE(0, 0);
  STAGE(1, 32);
#define O_STEP(SB, CB, KS)                                \
  STAGE(SB, (KS)*32);                                     \
  asm volatile("s_waitcnt vmcnt(8)" ::: "memory");        \
  wave_barrier();                                         \
  COMPUTE(CB);                                            \
  wave_barrier();
  for (int k3 = 0; k3 < 30; k3 += 3) {
    O_STEP(2, 0, k3 + 2)
    O_STEP(0, 1, k3 + 3)
    O_STEP(1, 2, k3 + 4)
  }
#undef O_STEP
  asm volatile("s_waitcnt vmcnt(4)" ::: "memory");
  wave_barrier();
  COMPUTE(0);                     // kstep 30
  wave_barrier();
  asm volatile("s_waitcnt vmcnt(0)" ::: "memory");
  wave_barrier();
  COMPUTE(1);                     // kstep 31

  // bias per output column (C/D layout: col=lane&15, row=quad*4+reg)
  float bvj[4];
#pragma unroll
  for (int j = 0; j < 4; ++j)
    bvj[j] = bias[s * D_ + n0 + wn * 64 + j * 16 + cl];

#pragma unroll
  for (int j = 0; j < 4; ++j) {
    const int col = n0 + wn * 64 + j * 16 + cl;
#pragma unroll
    for (int i = 0; i < 4; ++i) {
      const int rb = m0 + wm * 64 + i * 16 + quad * 4;
      float* Cf = C + (size_t)bs * (L_ * D_) + (size_t)rb * D_ + col;
#pragma unroll
      for (int r = 0; r < 4; ++r) Cf[(size_t)r * D_] = acc[i][j][r] + bvj[j];
    }
  }
}

// ------------- attention tile step (per-wave, no barrier) -------------------
__device__ __forceinline__ void attn_step(const ushort_t* __restrict__ Kbuf,
                                          const ushort_t* __restrict__ Vbuf,
                                          ushort_t* __restrict__ PTw,
                                          const short8 qa0, const short8 qa1,
                                          floatx4 (&o)[4], float& m_i, float& l_i,
                                          const bool diag, const int w,
                                          const int quad, const int cl) {
  floatx4 zero = {0.f, 0.f, 0.f, 0.f};
  const int sw0 = (quad ^ (cl & 7)) * 8;
  const int sw1 = ((4 + quad) ^ (cl & 7)) * 8;

  floatx4 st[4];
  __builtin_amdgcn_s_setprio(1);
#pragma unroll
  for (int j = 0; j < 4; ++j) {
    const int row = (j * 16 + cl) * 64;
    const short8 ka0 = *(const short8*)&Kbuf[row + sw0];
    const short8 ka1 = *(const short8*)&Kbuf[row + sw1];
    floatx4 z = zero;
    z = __builtin_amdgcn_mfma_f32_16x16x32_bf16(ka0, qa0, z, 0, 0, 0);
    z = __builtin_amdgcn_mfma_f32_16x16x32_bf16(ka1, qa1, z, 0, 0, 0);
    st[j] = z;
  }
  __builtin_amdgcn_s_setprio(0);

  if (diag) {  // causal mask on diagonal tile (kv_local > q_local)
    const int ql = w * 16 + cl;
#pragma unroll
    for (int j = 0; j < 4; ++j)
#pragma unroll
      for (int r = 0; r < 4; ++r)
        if (j * 16 + quad * 4 + r > ql) st[j][r] = -1e30f;
  }

  // per-lane max over 16 kv values (v_max3 tree) + 2 shfls across quads
  float t0 = fmax3(st[0][0], st[0][1], st[0][2]);
  float t1 = fmax3(st[0][3], st[1][0], st[1][1]);
  float t2 = fmax3(st[1][2], st[1][3], st[2][0]);
  float t3 = fmax3(st[2][1], st[2][2], st[2][3]);
  float t4 = fmax3(st[3][0], st[3][1], st[3][2]);
  float tm = fmaxf(fmax3(t0, t1, t2), fmax3(t3, t4, st[3][3]));
  tm = fmaxf(tm, __shfl_xor(tm, 16, 64));
  tm = fmaxf(tm, __shfl_xor(tm, 32, 64));
  const float mnew = fmaxf(m_i, tm);
  const float alpha = exp2f_fast(m_i - mnew);
  m_i = mnew;

  float tsv = 0.f;
#pragma unroll
  for (int j = 0; j < 4; ++j)
#pragma unroll
    for (int r = 0; r < 4; ++r) {
      st[j][r] = exp2f_fast(st[j][r] - mnew);
      tsv += st[j][r];
    }
  tsv += __shfl_xor(tsv, 16, 64);
  tsv += __shfl_xor(tsv, 32, 64);
  l_i = l_i * alpha + tsv;

  // P^T pairs -> per-wave LDS (b32 writes)
#pragma unroll
  for (int j = 0; j < 4; ++j) {
    const int base = cl * 72 + j * 16 + quad * 4;
    *(uint32_t*)&PTw[base] = pack_bf_trunc(st[j][0], st[j][1]);
    *(uint32_t*)&PTw[base + 2] = pack_bf_trunc(st[j][2], st[j][3]);
  }

#pragma unroll
  for (int j = 0; j < 4; ++j)
#pragma unroll
    for (int r = 0; r < 4; ++r) o[j][r] *= alpha;

  // O^T += V^T P^T
  const short8 pb0 = *(const short8*)&PTw[cl * 72 + quad * 8];
  const short8 pb1 = *(const short8*)&PTw[cl * 72 + 32 + quad * 8];
  __builtin_amdgcn_s_setprio(1);
#pragma unroll
  for (int j = 0; j < 4; ++j) {
    const int row = (j * 16 + cl) * 64;
    const short8 va0 = *(const short8*)&Vbuf[row + sw0];
    const short8 va1 = *(const short8*)&Vbuf[row + sw1];
    o[j] = __builtin_amdgcn_mfma_f32_16x16x32_bf16(va0, pb0, o[j], 0, 0, 0);
    o[j] = __builtin_amdgcn_mfma_f32_16x16x32_bf16(va1, pb1, o[j], 0, 0, 0);
  }
  __builtin_amdgcn_s_setprio(0);
}

__device__ __forceinline__ void attn_store(ushort_t* __restrict__ O, size_t act_base,
                                           int qt, int h, const floatx4 (&o)[4],
                                           float l_i, int w, int quad, int cl) {
  const float inv = 1.0f / l_i;
  ushort_t* Orow = O + act_base + (size_t)(qt * 64 + w * 16 + cl) * D_ + h * DK_;
#pragma unroll
  for (int j = 0; j < 4; ++j) {
    ushortx4 pk;
#pragma unroll
    for (int r = 0; r < 4; ++r) pk[r] = f2bf(o[j][r] * inv);
    *(ushortx4*)(Orow + j * 16 + quad * 4) = pk;
  }
}

// ------------- flash attention (dual-Q shared-KV) ---------------------------
__global__ __launch_bounds__(256) void attn_kernel(const ushort_t* __restrict__ Q,
                                                   const ushort_t* __restrict__ K,
                                                   const ushort_t* __restrict__ Vt,
                                                   ushort_t* __restrict__ O) {
  __shared__ __attribute__((aligned(16))) ushort_t Ks[2][64 * 64];   // [kv][dk] swz
  __shared__ __attribute__((aligned(16))) ushort_t Vts[2][64 * 64];  // [dk][kv] swz
  __shared__ __attribute__((aligned(16))) ushort_t PT[8][1152];      // per-wave A/B

  const int p = blockIdx.x, h = blockIdx.y, bs = blockIdx.z;
  const int t = threadIdx.x, lane = t & 63, w = t >> 6;
  const int quad = lane >> 4, cl = lane & 15;
  const size_t act_base = (size_t)bs * (L_ * D_);
  const int qtA = p, qtB = 15 - p;
  const int NIT = 16 - p;  // kv tiles 0..15-p

  const int cA = t, cB = t + 256;
  const int rA = cA >> 3, ccA = ((cA & 7) ^ (rA & 7)) * 8;
  const int rB = cB >> 3, ccB = ((cB & 7) ^ (rB & 7)) * 8;

  const ushort_t* pKA = K + act_base + (size_t)rA * D_ + h * DK_ + ccA;
  const ushort_t* pKB = K + act_base + (size_t)rB * D_ + h * DK_ + ccB;
  const ushort_t* pVA = Vt + act_base + (size_t)(h * DK_ + rA) * L_ + ccA;
  const ushort_t* pVB = Vt + act_base + (size_t)(h * DK_ + rB) * L_ + ccB;
  const size_t kstep = (size_t)64 * D_, vstep = 64;

  floatx4 zero = {0.f, 0.f, 0.f, 0.f};

  // Q fragments for both tiles (B-operand: lane=q-row, k contiguous)
  const ushort_t* QpA = Q + act_base + (size_t)(qtA * 64 + w * 16 + cl) * D_ + h * DK_ + quad * 8;
  const ushort_t* QpB = Q + act_base + (size_t)(qtB * 64 + w * 16 + cl) * D_ + h * DK_ + quad * 8;
  const short8 qaA0 = *(const short8*)QpA;
  const short8 qaA1 = *(const short8*)(QpA + 32);
  const short8 qaB0 = *(const short8*)QpB;
  const short8 qaB1 = *(const short8*)(QpB + 32);

  floatx4 oA[4], oB[4];
#pragma unroll
  for (int j = 0; j < 4; ++j) { oA[j] = zero; oB[j] = zero; }
  float mA = -3.0e38f, lA = 0.f, mB = -3.0e38f, lB = 0.f;

  // issue kv=0 into buf 0
  gl2lds16(pKA, &Ks[0][cA * 8]);
  gl2lds16(pKB, &Ks[0][cB * 8]);
  gl2lds16(pVA, &Vts[0][cA * 8]);
  gl2lds16(pVB, &Vts[0][cB * 8]);

  for (int kv = 0; kv < NIT; ++kv) {
    __syncthreads();  // drains buf[kv&1] loads; prior reads of other buf done
    if (kv + 1 < NIT) {
      pKA += kstep; pKB += kstep; pVA += vstep; pVB += vstep;
      const int nb = (kv + 1) & 1;
      gl2lds16(pKA, &Ks[nb][cA * 8]);
      gl2lds16(pKB, &Ks[nb][cB * 8]);
      gl2lds16(pVA, &Vts[nb][cA * 8]);
      gl2lds16(pVB, &Vts[nb][cB * 8]);
    }
    const int buf = kv & 1;

    if (kv <= p) {
      attn_step(Ks[buf], Vts[buf], PT[w], qaA0, qaA1, oA, mA, lA,
                kv == p, w, quad, cl);
      if (kv == p) attn_store(O, act_base, qtA, h, oA, lA, w, quad, cl);
    }
    attn_step(Ks[buf], Vts[buf], PT[w + 4], qaB0, qaB1, oB, mB, lB,
              kv == NIT - 1, w, quad, cl);
  }
  attn_store(O, act_base, qtB, h, oB, lB, w, quad, cl);
}

extern "C" void kernel_launch(void* const* d_in, const int* in_sizes, int n_in,
                              void* d_out, int out_size, void* d_ws, size_t ws_size,
                              hipStream_t stream) {
  const float* x  = (const float*)d_in[0];
  const float* Wq = (const float*)d_in[1];
  const float* Wk = (const float*)d_in[2];
  const float* Wv = (const float*)d_in[3];
  const float* Wo = (const float*)d_in[4];
  const float* bq = (const float*)d_in[5];
  const float* bk = (const float*)d_in[6];
  const float* bv = (const float*)d_in[7];
  const float* bo = (const float*)d_in[8];

  const size_t WT_SZ = (size_t)SPLIT_ * D_ * D_;  // 4 Mi elements
  const size_t ACT_SZ = (size_t)B_ * SEQ_ * D_;   // 16 Mi elements

  // ws layout (bf16): xbf[16Mi] | wt[4][4Mi] | Vt[16Mi]  => 96 MiB total
  ushort_t* ws0 = (ushort_t*)d_ws;
  ushort_t* xbf = ws0;
  ushort_t* wtall = xbf + ACT_SZ;
  ushort_t* wto = wtall + 3 * WT_SZ;
  ushort_t* Vtb = wtall + 4 * WT_SZ;
  // d_out (16Mi fp32 = 64 MiB) doubles as Q/K bf16 scratch until the final GEMM
  ushort_t* Qb = (ushort_t*)d_out;
  ushort_t* Kb = Qb + ACT_SZ;
  ushort_t* Ob = xbf;  // attention output reuses xbf (x dead after V projection)

  convert_x<<<ACT_SZ / 1024, 256, 0, stream>>>(x, xbf);
  wt_convert_all<<<dim3(32, 32, 16), dim3(32, 8, 1), 0, stream>>>(Wq, Wk, Wv, Wo, wtall);

  // fused Q/K/V projection: one launch, shared A, 3-deep counted-vmcnt pipeline
  gemm_qkv<<<dim3(8, 256, 1), dim3(256, 1, 1), 0, stream>>>(
      xbf, wtall, bq, bk, bv, Qb, Kb, Vtb);

  dim3 ag(8, 16, 16);
  attn_kernel<<<ag, dim3(256, 1, 1), 0, stream>>>(Qb, Kb, Vtb, Ob);

  gemm_o<<<dim3(8, 128, 1), dim3(256, 1, 1), 0, stream>>>(Ob, wto, bo, (float*)d_out);
}